// Round 8
// baseline (359.622 us; speedup 1.0000x reference)
//
#include <hip/hip_runtime.h>

#define LOG2E 1.44269504088896340736f

__device__ __forceinline__ float fast_exp2(float x) {
#if __has_builtin(__builtin_amdgcn_exp2f)
    return __builtin_amdgcn_exp2f(x);
#else
    return exp2f(x);
#endif
}

constexpr int BATCH = 32;
constexpr int CH = 3;
constexpr int KPAL = 32;
constexpr int PIX_PER_BATCH = 256 * 256;            // 65536
constexpr int THREADS = 256;
constexpr int PIX_PER_THREAD = 4;
constexpr int BLOCKS_PER_BATCH = PIX_PER_BATCH / (THREADS * PIX_PER_THREAD);  // 64
constexpr int NBLOCKS = BATCH * BLOCKS_PER_BATCH;   // 2048

// 4 pixels per thread to amortize the per-k LDS broadcast (Round-6 lesson:
// 32 ds_read_b128 per *pixel* made the LDS pipe the bottleneck, ~20+ us of
// pure LDS occupancy chip-wide). ALL state is named scalars — no indexed
// arrays — so nothing can be demoted to scratch (Round-2 lesson: spill
// traffic cost 24x).
// Math: softmax over K with |x|^2 dropped (shift-invariant), exp2-native,
// combine accumulated against pre-scaled palette coeffs, fixed up by one
// final scale r = (T/(2*log2e)) / sum.
__global__ __launch_bounds__(THREADS, 8)
void palette_quant_kernel(const float* __restrict__ images,
                          const float* __restrict__ palettes,
                          const float* __restrict__ temp,
                          float* __restrict__ out)
{
    __shared__ float4 ab[KPAL];   // (a0, a1, a2, b) per palette entry
    __shared__ float s_fs;        // final-scale constant T/(2*log2e)

    const int batch = blockIdx.x >> 6;   // / BLOCKS_PER_BATCH

    if (threadIdx.x < KPAL) {
        const float T = *temp;
        const float cinv = LOG2E / T;
        const float* p = palettes + (batch * KPAL + threadIdx.x) * CH;
        const float p0 = p[0], p1 = p[1], p2 = p[2];
        const float b = -(p0 * p0 + p1 * p1 + p2 * p2) * cinv;
        const float c2 = 2.0f * cinv;
        ab[threadIdx.x] = make_float4(p0 * c2, p1 * c2, p2 * c2, b);
        if (threadIdx.x == 0) s_fs = T * (0.5f / LOG2E);
    }
    __syncthreads();

    const int tid = ((blockIdx.x & 63) << 8) | threadIdx.x;  // 0..16383 within batch
    const long long base = (long long)batch * (PIX_PER_BATCH * CH)
                         + (long long)tid * (PIX_PER_THREAD * CH);

    const float4* ip = reinterpret_cast<const float4*>(images + base);
    const float4 v0 = ip[0];
    const float4 v1 = ip[1];
    const float4 v2 = ip[2];

    // De-interleave 4 pixels' RGB into NAMED scalars (no arrays!).
    const float xA0 = v0.x, xA1 = v0.y, xA2 = v0.z;
    const float xB0 = v0.w, xB1 = v1.x, xB2 = v1.y;
    const float xC0 = v1.z, xC1 = v1.w, xC2 = v2.x;
    const float xD0 = v2.y, xD1 = v2.z, xD2 = v2.w;

    float sumA = 0.f, oA0 = 0.f, oA1 = 0.f, oA2 = 0.f;
    float sumB = 0.f, oB0 = 0.f, oB1 = 0.f, oB2 = 0.f;
    float sumC = 0.f, oC0 = 0.f, oC1 = 0.f, oC2 = 0.f;
    float sumD = 0.f, oD0 = 0.f, oD1 = 0.f, oD2 = 0.f;

#define PIX_STEP(X0, X1, X2, SUM, O0, O1, O2)                 \
    {                                                         \
        float s = fmaf((X0), a.x, a.w);                       \
        s = fmaf((X1), a.y, s);                               \
        s = fmaf((X2), a.z, s);                               \
        const float w = fast_exp2(s);                         \
        (SUM) += w;                                           \
        (O0) = fmaf(w, a.x, (O0));                            \
        (O1) = fmaf(w, a.y, (O1));                            \
        (O2) = fmaf(w, a.z, (O2));                            \
    }

#pragma unroll
    for (int k = 0; k < KPAL; ++k) {
        const float4 a = ab[k];   // uniform addr -> one ds_read_b128 broadcast per k
        PIX_STEP(xA0, xA1, xA2, sumA, oA0, oA1, oA2)
        PIX_STEP(xB0, xB1, xB2, sumB, oB0, oB1, oB2)
        PIX_STEP(xC0, xC1, xC2, sumC, oC0, oC1, oC2)
        PIX_STEP(xD0, xD1, xD2, sumD, oD0, oD1, oD2)
    }
#undef PIX_STEP

    const float fs = s_fs;
    const float rA = fs * __builtin_amdgcn_rcpf(sumA);
    const float rB = fs * __builtin_amdgcn_rcpf(sumB);
    const float rC = fs * __builtin_amdgcn_rcpf(sumC);
    const float rD = fs * __builtin_amdgcn_rcpf(sumD);

    const float4 w0 = make_float4(oA0 * rA, oA1 * rA, oA2 * rA, oB0 * rB);
    const float4 w1 = make_float4(oB1 * rB, oB2 * rB, oC0 * rC, oC1 * rC);
    const float4 w2 = make_float4(oC2 * rC, oD0 * rD, oD1 * rD, oD2 * rD);

    float4* op = reinterpret_cast<float4*>(out + base);
    op[0] = w0;
    op[1] = w1;
    op[2] = w2;
}

extern "C" void kernel_launch(void* const* d_in, const int* in_sizes, int n_in,
                              void* d_out, int out_size, void* d_ws, size_t ws_size,
                              hipStream_t stream) {
    const float* images   = (const float*)d_in[0];
    const float* palettes = (const float*)d_in[1];
    const float* temp     = (const float*)d_in[2];
    float* out            = (float*)d_out;

    palette_quant_kernel<<<dim3(NBLOCKS), dim3(THREADS), 0, stream>>>(
        images, palettes, temp, out);
}

// Round 9
// 90.609 us; speedup vs baseline: 3.9690x; 3.9690x over previous
//
#include <hip/hip_runtime.h>

#define LOG2E 1.44269504088896340736f

__device__ __forceinline__ float fast_exp2(float x) {
#if __has_builtin(__builtin_amdgcn_exp2f)
    return __builtin_amdgcn_exp2f(x);
#else
    return exp2f(x);
#endif
}

constexpr int BATCH = 32;
constexpr int CH = 3;
constexpr int KPAL = 32;
constexpr int PIX_PER_BATCH = 256 * 256;            // 65536
constexpr int THREADS = 256;
constexpr int PIX_PER_THREAD = 4;
constexpr int BLOCKS_PER_BATCH = PIX_PER_BATCH / (THREADS * PIX_PER_THREAD);  // 64
constexpr int NBLOCKS = BATCH * BLOCKS_PER_BATCH;   // 2048

// ROUND-9 CHANGE (single, for clean A/B): __launch_bounds__ 8 -> 4 waves/EU.
// Evidence: R2 and R8 (both ~50 live values) both compiled to VGPR_Count=32
// with ~1.2 GB of scratch spill traffic and ~355 us; R6 (~12 live values)
// fit in 32 VGPRs and ran clean. The (256,8) bound caps the allocator at 32
// VGPRs on this toolchain and it spills instead of trading occupancy.
// (256,4) -> ~128 VGPR budget, 16 waves/CU — plenty of both.
//
// Structure: 4 pixels/thread amortizes the per-k LDS broadcast (one
// ds_read_b128 per k serves 4 pixels). All state in named scalars.
// Math: softmax over K with |x|^2 dropped (shift-invariant), exp2-native,
// combine accumulated against pre-scaled palette coeffs, fixed up by one
// final scale r = (T/(2*log2e)) / sum.
__global__ __launch_bounds__(THREADS, 4)
void palette_quant_kernel(const float* __restrict__ images,
                          const float* __restrict__ palettes,
                          const float* __restrict__ temp,
                          float* __restrict__ out)
{
    __shared__ float4 ab[KPAL];   // (a0, a1, a2, b) per palette entry
    __shared__ float s_fs;        // final-scale constant T/(2*log2e)

    const int batch = blockIdx.x >> 6;   // / BLOCKS_PER_BATCH

    if (threadIdx.x < KPAL) {
        const float T = *temp;
        const float cinv = LOG2E / T;
        const float* p = palettes + (batch * KPAL + threadIdx.x) * CH;
        const float p0 = p[0], p1 = p[1], p2 = p[2];
        const float b = -(p0 * p0 + p1 * p1 + p2 * p2) * cinv;
        const float c2 = 2.0f * cinv;
        ab[threadIdx.x] = make_float4(p0 * c2, p1 * c2, p2 * c2, b);
        if (threadIdx.x == 0) s_fs = T * (0.5f / LOG2E);
    }
    __syncthreads();

    const int tid = ((blockIdx.x & 63) << 8) | threadIdx.x;  // 0..16383 within batch
    const long long base = (long long)batch * (PIX_PER_BATCH * CH)
                         + (long long)tid * (PIX_PER_THREAD * CH);

    const float4* ip = reinterpret_cast<const float4*>(images + base);
    const float4 v0 = ip[0];
    const float4 v1 = ip[1];
    const float4 v2 = ip[2];

    // De-interleave 4 pixels' RGB into NAMED scalars (no arrays!).
    const float xA0 = v0.x, xA1 = v0.y, xA2 = v0.z;
    const float xB0 = v0.w, xB1 = v1.x, xB2 = v1.y;
    const float xC0 = v1.z, xC1 = v1.w, xC2 = v2.x;
    const float xD0 = v2.y, xD1 = v2.z, xD2 = v2.w;

    float sumA = 0.f, oA0 = 0.f, oA1 = 0.f, oA2 = 0.f;
    float sumB = 0.f, oB0 = 0.f, oB1 = 0.f, oB2 = 0.f;
    float sumC = 0.f, oC0 = 0.f, oC1 = 0.f, oC2 = 0.f;
    float sumD = 0.f, oD0 = 0.f, oD1 = 0.f, oD2 = 0.f;

#define PIX_STEP(X0, X1, X2, SUM, O0, O1, O2)                 \
    {                                                         \
        float s = fmaf((X0), a.x, a.w);                       \
        s = fmaf((X1), a.y, s);                               \
        s = fmaf((X2), a.z, s);                               \
        const float w = fast_exp2(s);                         \
        (SUM) += w;                                           \
        (O0) = fmaf(w, a.x, (O0));                            \
        (O1) = fmaf(w, a.y, (O1));                            \
        (O2) = fmaf(w, a.z, (O2));                            \
    }

#pragma unroll
    for (int k = 0; k < KPAL; ++k) {
        const float4 a = ab[k];   // uniform addr -> one ds_read_b128 broadcast per k
        PIX_STEP(xA0, xA1, xA2, sumA, oA0, oA1, oA2)
        PIX_STEP(xB0, xB1, xB2, sumB, oB0, oB1, oB2)
        PIX_STEP(xC0, xC1, xC2, sumC, oC0, oC1, oC2)
        PIX_STEP(xD0, xD1, xD2, sumD, oD0, oD1, oD2)
    }
#undef PIX_STEP

    const float fs = s_fs;
    const float rA = fs * __builtin_amdgcn_rcpf(sumA);
    const float rB = fs * __builtin_amdgcn_rcpf(sumB);
    const float rC = fs * __builtin_amdgcn_rcpf(sumC);
    const float rD = fs * __builtin_amdgcn_rcpf(sumD);

    const float4 w0 = make_float4(oA0 * rA, oA1 * rA, oA2 * rA, oB0 * rB);
    const float4 w1 = make_float4(oB1 * rB, oB2 * rB, oC0 * rC, oC1 * rC);
    const float4 w2 = make_float4(oC2 * rC, oD0 * rD, oD1 * rD, oD2 * rD);

    float4* op = reinterpret_cast<float4*>(out + base);
    op[0] = w0;
    op[1] = w1;
    op[2] = w2;
}

extern "C" void kernel_launch(void* const* d_in, const int* in_sizes, int n_in,
                              void* d_out, int out_size, void* d_ws, size_t ws_size,
                              hipStream_t stream) {
    const float* images   = (const float*)d_in[0];
    const float* palettes = (const float*)d_in[1];
    const float* temp     = (const float*)d_in[2];
    float* out            = (float*)d_out;

    palette_quant_kernel<<<dim3(NBLOCKS), dim3(THREADS), 0, stream>>>(
        images, palettes, temp, out);
}